// Round 21
// baseline (62.826 us; speedup 1.0000x reference)
//
#include <hip/hip_runtime.h>
#include <stdint.h>

#define NTOK 8192
#define NCOL 4096     // DIM == VOCAB
#define RANK 256

typedef __attribute__((ext_vector_type(8))) short bf16x8;
typedef __attribute__((ext_vector_type(4))) float f32x4;

__device__ __forceinline__ unsigned short f2bf(float f) {
    unsigned int u = __float_as_uint(f);
    u += 0x7fffu + ((u >> 16) & 1u);   // RNE
    return (unsigned short)(u >> 16);
}
__device__ __forceinline__ float bf2f(unsigned int u16) {
    return __uint_as_float(u16 << 16);
}

// async global->LDS, 16B per lane (fallback path only)
__device__ __forceinline__ void gload_lds16(const uint4* g, uint4* l) {
    __builtin_amdgcn_global_load_lds(
        (const __attribute__((address_space(1))) void*)g,
        (__attribute__((address_space(3))) void*)l, 16, 0, 0);
}

// ---- pre-pass: A fp32 -> bf16 rows (Abf); B fp32 -> bf16 MFMA-frag (Bfrag) ----
__global__ __launch_bounds__(256) void prep_kernel(
    const float* __restrict__ A, const float* __restrict__ B,
    unsigned short* __restrict__ Abf, unsigned short* __restrict__ Bfrag)
{
    if (blockIdx.x < 1024) {
        int i = blockIdx.x * 256 + threadIdx.x;
        float4 v = reinterpret_cast<const float4*>(A)[i];
        ushort4 o;
        o.x = f2bf(v.x); o.y = f2bf(v.y); o.z = f2bf(v.z); o.w = f2bf(v.w);
        reinterpret_cast<ushort4*>(Abf)[i] = o;
    } else {
        int gt = (blockIdx.x - 1024) * 256 + threadIdx.x;
        int ct = gt >> 9;
        int rem = gt & 511;
        int ks = rem >> 6;
        int ln = rem & 63;
        int col = ct * 16 + (ln & 15);
        int kb  = ks * 32 + ((ln >> 4) << 3);
        unsigned short pk[8];
        #pragma unroll
        for (int j = 0; j < 8; ++j)
            pk[j] = f2bf(B[(size_t)(kb + j) * NCOL + col]);
        uint4 o;
        o.x = (unsigned)pk[0] | ((unsigned)pk[1] << 16);
        o.y = (unsigned)pk[2] | ((unsigned)pk[3] << 16);
        o.z = (unsigned)pk[4] | ((unsigned)pk[5] << 16);
        o.w = (unsigned)pk[6] | ((unsigned)pk[7] << 16);
        reinterpret_cast<uint4*>(Bfrag)[gt] = o;
    }
}

// ---- P1: lora_bf16[4096][4096] = bf16(A @ B) over the VOCAB (no gather,
// no mask, no W): 8.6 GF, half the fused kernel's matrix work. No LDS, no
// barriers — waves fully independent; B-frags served from L2 (2 MiB).
__global__ __launch_bounds__(256) void p1_gemm(
    const unsigned short* __restrict__ Abf,
    const unsigned short* __restrict__ Bfrag,
    unsigned short* __restrict__ loraBf)
{
    const int tid  = threadIdx.x;
    const int lane = tid & 63;
    const int wave = tid >> 6;            // wave owns rows [wave*32, +32)
    const int row0 = blockIdx.x * 128;
    const int col0 = blockIdx.y * 256;

    const int a0row = row0 + wave * 32 + (lane & 15);
    const int a1row = a0row + 16;
    const unsigned short* ap0 = Abf + (size_t)a0row * RANK + ((lane >> 4) << 3);
    const unsigned short* ap1 = Abf + (size_t)a1row * RANK + ((lane >> 4) << 3);
    bf16x8 aA[8], aB[8];
    #pragma unroll
    for (int s = 0; s < 8; ++s) {
        aA[s] = *reinterpret_cast<const bf16x8*>(ap0 + s * 32);
        aB[s] = *reinterpret_cast<const bf16x8*>(ap1 + s * 32);
    }

    const int colb = col0 + (lane & 15);
    const int rb0  = row0 + wave * 32 + ((lane >> 4) << 2);   // group0 rows
    unsigned obase0 = (unsigned)rb0 * NCOL + colb;
    unsigned obase1 = (unsigned)(rb0 + 16) * NCOL + colb;

    const uint4* bcol = reinterpret_cast<const uint4*>(Bfrag)
                        + (size_t)(blockIdx.y * 16) * 512 + lane;

    #pragma unroll 1
    for (int t = 0; t < 16; ++t) {
        uint4 bb[8];
        #pragma unroll
        for (int s = 0; s < 8; ++s)
            bb[s] = bcol[t * 512 + s * 64];
        f32x4 acc00 = {0.f,0.f,0.f,0.f}, acc01 = {0.f,0.f,0.f,0.f};
        f32x4 acc10 = {0.f,0.f,0.f,0.f}, acc11 = {0.f,0.f,0.f,0.f};
        #pragma unroll
        for (int s = 0; s < 4; ++s) {
            bf16x8 b0 = __builtin_bit_cast(bf16x8, bb[s]);
            bf16x8 b1 = __builtin_bit_cast(bf16x8, bb[s + 4]);
            acc00 = __builtin_amdgcn_mfma_f32_16x16x32_bf16(aA[s],     b0, acc00, 0, 0, 0);
            acc01 = __builtin_amdgcn_mfma_f32_16x16x32_bf16(aA[s + 4], b1, acc01, 0, 0, 0);
            acc10 = __builtin_amdgcn_mfma_f32_16x16x32_bf16(aB[s],     b0, acc10, 0, 0, 0);
            acc11 = __builtin_amdgcn_mfma_f32_16x16x32_bf16(aB[s + 4], b1, acc11, 0, 0, 0);
        }
        #pragma unroll
        for (int r = 0; r < 4; ++r) {
            loraBf[obase0 + r * NCOL + t * 16] = f2bf(acc00[r] + acc01[r]);
            loraBf[obase1 + r * NCOL + t * 16] = f2bf(acc10[r] + acc11[r]);
        }
    }
}

// ---- P2: pure streaming gather. out[tok] = mask ? 0 : W[idx] + lora[idx].
// One block per token row; no barriers, no MFMA, fully coalesced float4.
__global__ __launch_bounds__(256) void p2_gather(
    const int* __restrict__ x,
    const int* __restrict__ mask,
    const float* __restrict__ W,
    const unsigned short* __restrict__ loraBf,
    float* __restrict__ out)
{
    const int tok = blockIdx.x;
    const int tid = threadIdx.x;
    float4* orow = reinterpret_cast<float4*>(out + (size_t)tok * NCOL) + tid;

    if (mask[tok]) {
        float4 z = {0.f, 0.f, 0.f, 0.f};
        #pragma unroll
        for (int k = 0; k < 4; ++k) orow[k * 256] = z;
    } else {
        const int idx = x[tok];
        const float4* wrow = reinterpret_cast<const float4*>(
            W + (size_t)idx * NCOL) + tid;
        const uint2* lrow = reinterpret_cast<const uint2*>(
            loraBf + (size_t)idx * NCOL) + tid;
        #pragma unroll
        for (int k = 0; k < 4; ++k) {
            float4 wv = wrow[k * 256];
            uint2  lv = lrow[k * 256];
            float4 o;
            o.x = wv.x + bf2f(lv.x & 0xffffu);
            o.y = wv.y + bf2f(lv.x >> 16);
            o.z = wv.z + bf2f(lv.y & 0xffffu);
            o.w = wv.w + bf2f(lv.y >> 16);
            orow[k * 256] = o;
        }
    }
}

// ---- fallback: proven fused kernel (r15-style, ~49.4 us) if ws too small ----
__global__ __launch_bounds__(256) void emb_lora_fused_fb(
    const int* __restrict__ x, const int* __restrict__ mask,
    const float* __restrict__ W,
    const unsigned short* __restrict__ Abf,
    const unsigned short* __restrict__ Bfrag,
    float* __restrict__ out)
{
    __shared__ int s_idx[128];
    __shared__ int s_msk[128];
    __shared__ uint4 b_lds[2][512];

    const int tid  = threadIdx.x;
    const int lane = tid & 63;
    const int wave = tid >> 6;
    const int tok0 = blockIdx.x * 128;
    const int col0 = blockIdx.y * 256;

    if (tid < 128) { s_idx[tid] = x[tok0 + tid]; s_msk[tid] = mask[tok0 + tid]; }
    __syncthreads();

    const int a0row = s_idx[wave * 32 + (lane & 15)];
    const int a1row = s_idx[wave * 32 + 16 + (lane & 15)];
    const unsigned short* ap0 = Abf + (size_t)a0row * RANK + ((lane >> 4) << 3);
    const unsigned short* ap1 = Abf + (size_t)a1row * RANK + ((lane >> 4) << 3);
    bf16x8 aA[8], aB[8];
    #pragma unroll
    for (int s = 0; s < 8; ++s) {
        aA[s] = *reinterpret_cast<const bf16x8*>(ap0 + s * 32);
        aB[s] = *reinterpret_cast<const bf16x8*>(ap1 + s * 32);
    }

    const int colb = col0 + (lane & 15);
    int msk0[4], msk1[4];
    unsigned woff0[4], woff1[4], ooff0[4], ooff1[4];
    #pragma unroll
    for (int r = 0; r < 4; ++r) {
        int row0 = wave * 32 + ((lane >> 4) << 2) + r;
        int row1 = row0 + 16;
        msk0[r] = s_msk[row0]; msk1[r] = s_msk[row1];
        woff0[r] = (unsigned)s_idx[row0] * NCOL + colb;
        woff1[r] = (unsigned)s_idx[row1] * NCOL + colb;
        ooff0[r] = (unsigned)(tok0 + row0) * NCOL + colb;
        ooff1[r] = (unsigned)(tok0 + row1) * NCOL + colb;
    }

    const uint4* bpanel = reinterpret_cast<const uint4*>(Bfrag)
                          + (size_t)(blockIdx.y * 16) * 512;
    float wv0[4][4], wv1[4][4];
    #pragma unroll
    for (int p = 0; p < 4; ++p)
        #pragma unroll
        for (int r = 0; r < 4; ++r) {
            float v0 = 0.0f, v1 = 0.0f;
            if (!msk0[r]) v0 = W[woff0[r] + p * 16];
            if (!msk1[r]) v1 = W[woff1[r] + p * 16];
            wv0[p][r] = v0; wv1[p][r] = v1;
        }

#define STAGE_FB(T, BUF)                                                 \
    {                                                                    \
        const uint4* gs = bpanel + (T) * 512 + wave * 128 + lane;        \
        gload_lds16(gs,      &b_lds[BUF][wave * 128]);                   \
        gload_lds16(gs + 64, &b_lds[BUF][wave * 128 + 64]);              \
    }
    STAGE_FB(0, 0);
    __syncthreads();

#define TILE_FB(T, BUF, SLOT, PF, LAST)                                  \
    {                                                                    \
        const int t_ = (T);                                              \
        float wc0[4], wc1[4];                                            \
        _Pragma("unroll")                                                \
        for (int r = 0; r < 4; ++r) { wc0[r] = wv0[SLOT][r]; wc1[r] = wv1[SLOT][r]; } \
        if (PF) {                                                        \
            _Pragma("unroll")                                            \
            for (int r = 0; r < 4; ++r) {                                \
                float v0 = 0.0f, v1 = 0.0f;                              \
                if (!msk0[r]) v0 = W[woff0[r] + (t_ + 4) * 16];          \
                if (!msk1[r]) v1 = W[woff1[r] + (t_ + 4) * 16];          \
                wv0[SLOT][r] = v0; wv1[SLOT][r] = v1;                    \
            }                                                            \
        }                                                                \
        if (!(LAST)) { STAGE_FB(t_ + 1, 1 - (BUF)); }                    \
        __builtin_amdgcn_sched_barrier(0);                               \
        uint4 bb[8];                                                     \
        _Pragma("unroll")                                                \
        for (int s = 0; s < 8; ++s) bb[s] = b_lds[BUF][s * 64 + lane];   \
        f32x4 acc00 = {0.f,0.f,0.f,0.f}, acc01 = {0.f,0.f,0.f,0.f};      \
        f32x4 acc10 = {0.f,0.f,0.f,0.f}, acc11 = {0.f,0.f,0.f,0.f};      \
        _Pragma("unroll")                                                \
        for (int s = 0; s < 4; ++s) {                                    \
            bf16x8 b0 = __builtin_bit_cast(bf16x8, bb[s]);               \
            bf16x8 b1 = __builtin_bit_cast(bf16x8, bb[s + 4]);           \
            acc00 = __builtin_amdgcn_mfma_f32_16x16x32_bf16(aA[s],     b0, acc00, 0, 0, 0); \
            acc01 = __builtin_amdgcn_mfma_f32_16x16x32_bf16(aA[s + 4], b1, acc01, 0, 0, 0); \
            acc10 = __builtin_amdgcn_mfma_f32_16x16x32_bf16(aB[s],     b0, acc10, 0, 0, 0); \
            acc11 = __builtin_amdgcn_mfma_f32_16x16x32_bf16(aB[s + 4], b1, acc11, 0, 0, 0); \
        }                                                                \
        _Pragma("unroll")                                                \
        for (int r = 0; r < 4; ++r) {                                    \
            float v0 = msk0[r] ? 0.0f : (acc00[r] + acc01[r] + wc0[r]);  \
            float v1 = msk1[r] ? 0.0f : (acc10[r] + acc11[r] + wc1[r]);  \
            out[ooff0[r] + t_ * 16] = v0;                                \
            out[ooff1[r] + t_ * 16] = v1;                                \
        }                                                                \
        if (!(LAST)) {                                                   \
            asm volatile("s_waitcnt vmcnt(8)" ::: "memory");             \
            __builtin_amdgcn_s_barrier();                                \
        }                                                                \
    }
    TILE_FB(0,  0, 0, 1, 0); TILE_FB(1,  1, 1, 1, 0);
    TILE_FB(2,  0, 2, 1, 0); TILE_FB(3,  1, 3, 1, 0);
    TILE_FB(4,  0, 0, 1, 0); TILE_FB(5,  1, 1, 1, 0);
    TILE_FB(6,  0, 2, 1, 0); TILE_FB(7,  1, 3, 1, 0);
    TILE_FB(8,  0, 0, 1, 0); TILE_FB(9,  1, 1, 1, 0);
    TILE_FB(10, 0, 2, 1, 0); TILE_FB(11, 1, 3, 1, 0);
    TILE_FB(12, 0, 0, 0, 0); TILE_FB(13, 1, 1, 0, 0);
    TILE_FB(14, 0, 2, 0, 0); TILE_FB(15, 1, 3, 0, 1);
#undef TILE_FB
#undef STAGE_FB
}

extern "C" void kernel_launch(void* const* d_in, const int* in_sizes, int n_in,
                              void* d_out, int out_size, void* d_ws, size_t ws_size,
                              hipStream_t stream) {
    (void)in_sizes; (void)n_in; (void)out_size;

    const int*   x    = (const int*)d_in[0];
    const int*   mask = (const int*)d_in[1];
    const float* W    = (const float*)d_in[2];
    const float* A    = (const float*)d_in[3];
    const float* B    = (const float*)d_in[4];
    float*       out  = (float*)d_out;

    unsigned short* Abf   = (unsigned short*)d_ws;                       // 2 MiB
    unsigned short* Bfrag = (unsigned short*)((char*)d_ws + (2u << 20)); // 2 MiB

    prep_kernel<<<dim3(1536), dim3(256), 0, stream>>>(A, B, Abf, Bfrag);

    const size_t need = (4u << 20) + (size_t)NCOL * NCOL * 2;  // +32 MiB lora
    if (ws_size >= need) {
        unsigned short* loraBf = (unsigned short*)((char*)d_ws + (4u << 20));
        p1_gemm<<<dim3(32, 16), dim3(256), 0, stream>>>(Abf, Bfrag, loraBf);
        p2_gather<<<dim3(NTOK), dim3(256), 0, stream>>>(x, mask, W, loraBf, out);
    } else {
        emb_lora_fused_fb<<<dim3(64, 16), dim3(256), 0, stream>>>(
            x, mask, W, Abf, Bfrag, out);
    }
}

// Round 22
// 55.473 us; speedup vs baseline: 1.1325x; 1.1325x over previous
//
#include <hip/hip_runtime.h>
#include <stdint.h>

#define NTOK 8192
#define NCOL 4096     // DIM == VOCAB
#define RANK 256
#define TPB  128      // tokens per block (4 waves x 32 tokens)
#define CPB  256      // cols per block (16 col-tiles)

typedef __attribute__((ext_vector_type(8))) short bf16x8;
typedef __attribute__((ext_vector_type(4))) float f32x4;

__device__ __forceinline__ unsigned short f2bf(float f) {
    unsigned int u = __float_as_uint(f);
    u += 0x7fffu + ((u >> 16) & 1u);   // RNE
    return (unsigned short)(u >> 16);
}

__device__ __forceinline__ bf16x8 pack8(float4 lo, float4 hi) {
    union { unsigned short u[8]; bf16x8 v; } r;
    r.u[0] = f2bf(lo.x); r.u[1] = f2bf(lo.y);
    r.u[2] = f2bf(lo.z); r.u[3] = f2bf(lo.w);
    r.u[4] = f2bf(hi.x); r.u[5] = f2bf(hi.y);
    r.u[6] = f2bf(hi.z); r.u[7] = f2bf(hi.w);
    return r.v;
}

// async global->LDS, 16B per lane; LDS dest = uniform base + lane*16 (m104)
__device__ __forceinline__ void gload_lds16(const uint4* g, uint4* l) {
    __builtin_amdgcn_global_load_lds(
        (const __attribute__((address_space(1))) void*)g,
        (__attribute__((address_space(3))) void*)l, 16, 0, 0);
}

// ---- pre-pass (B only now; A-cast folded into main prologue) ----
// B fp32 [256][4096] -> bf16 MFMA-B-fragment order:
//   flat uint4 index = (ct*8 + ks)*64 + lane, 8 bf16 each:
//     element j = B[ks*32 + (lane>>4)*8 + j][ct*16 + (lane&15)]
__global__ __launch_bounds__(256) void prep_B_kernel(
    const float* __restrict__ B, unsigned short* __restrict__ Bfrag)
{
    int gt = blockIdx.x * 256 + threadIdx.x;   // 131072 threads
    int ct = gt >> 9;
    int rem = gt & 511;
    int ks = rem >> 6;
    int ln = rem & 63;
    int col = ct * 16 + (ln & 15);
    int kb  = ks * 32 + ((ln >> 4) << 3);
    unsigned short pk[8];
    #pragma unroll
    for (int j = 0; j < 8; ++j)
        pk[j] = f2bf(B[(size_t)(kb + j) * NCOL + col]);
    uint4 o;
    o.x = (unsigned)pk[0] | ((unsigned)pk[1] << 16);
    o.y = (unsigned)pk[2] | ((unsigned)pk[3] << 16);
    o.z = (unsigned)pk[4] | ((unsigned)pk[5] << 16);
    o.w = (unsigned)pk[6] | ((unsigned)pk[7] << 16);
    reinterpret_cast<uint4*>(Bfrag)[gt] = o;
}

// ---- main: fused gather + LoRA GEMM + W add + mask ----
// r17 structure exactly (best: 49.09 us — LDS-staged B, 2-tile phases with
// 4 buffers, W-ring depth 4, counted vmcnt(16) + raw barrier), with the
// A-cast folded in: A fragments gathered as fp32 from A and packed to bf16
// in registers (removes 1024 prep blocks from the timed path).
__global__ __launch_bounds__(256) void emb_lora_mfma(
    const int* __restrict__ x,
    const int* __restrict__ mask,
    const float* __restrict__ W,
    const float* __restrict__ A,
    const unsigned short* __restrict__ Bfrag,
    float* __restrict__ out)
{
    __shared__ int s_idx[TPB];
    __shared__ int s_msk[TPB];
    __shared__ uint4 b_lds[4][512];   // 4 x 8 KB staging buffers

    const int tid  = threadIdx.x;
    const int lane = tid & 63;
    const int wave = tid >> 6;        // wave owns tokens [wave*32, wave*32+32)
    const int tok0 = blockIdx.x * TPB;
    const int col0 = blockIdx.y * CPB;

    if (tid < TPB) {
        s_idx[tid] = x[tok0 + tid];
        s_msk[tid] = mask[tok0 + tid];
    }
    __syncthreads();

    // A fragments for both token groups, gathered fp32 -> packed bf16 in-reg
    const int a0row = s_idx[wave * 32 + (lane & 15)];
    const int a1row = s_idx[wave * 32 + 16 + (lane & 15)];
    const float* ap0 = A + (size_t)a0row * RANK + ((lane >> 4) << 3);
    const float* ap1 = A + (size_t)a1row * RANK + ((lane >> 4) << 3);
    bf16x8 aA[8], aB[8];
    #pragma unroll
    for (int s = 0; s < 8; ++s) {
        float4 l0 = *reinterpret_cast<const float4*>(ap0 + s * 32);
        float4 h0 = *reinterpret_cast<const float4*>(ap0 + s * 32 + 4);
        float4 l1 = *reinterpret_cast<const float4*>(ap1 + s * 32);
        float4 h1 = *reinterpret_cast<const float4*>(ap1 + s * 32 + 4);
        aA[s] = pack8(l0, h0);
        aB[s] = pack8(l1, h1);
    }

    // per-thread epilogue state: group g covers rows wave*32+g*16+(lane>>4)*4+r
    const int colb = col0 + (lane & 15);
    int msk0[4], msk1[4];
    unsigned woff0[4], woff1[4], ooff0[4], ooff1[4];
    #pragma unroll
    for (int r = 0; r < 4; ++r) {
        int row0 = wave * 32 + ((lane >> 4) << 2) + r;
        int row1 = row0 + 16;
        msk0[r] = s_msk[row0];
        msk1[r] = s_msk[row1];
        woff0[r] = (unsigned)s_idx[row0] * NCOL + colb;
        woff1[r] = (unsigned)s_idx[row1] * NCOL + colb;
        ooff0[r] = (unsigned)(tok0 + row0) * NCOL + colb;
        ooff1[r] = (unsigned)(tok0 + row1) * NCOL + colb;
    }

    // block's 16 col-tiles start at global col-tile blockIdx.y*16
    const uint4* bpanel = reinterpret_cast<const uint4*>(Bfrag)
                          + (size_t)(blockIdx.y * 16) * 512;

    // W prefetch rings, depth 4, exec-masked loads
    // (explicit `if`, NOT ternary — r3: speculation doubled FETCH_SIZE)
    float wv0[4][4], wv1[4][4];
    #pragma unroll
    for (int p = 0; p < 4; ++p) {
        #pragma unroll
        for (int r = 0; r < 4; ++r) {
            float v0 = 0.0f, v1 = 0.0f;
            if (!msk0[r]) v0 = W[woff0[r] + p * 16];
            if (!msk1[r]) v1 = W[woff1[r] + p * 16];
            wv0[p][r] = v0;
            wv1[p][r] = v1;
        }
    }

    // stage: wave stages its 2 KB of tile T into buffer BUF (async)
#define STAGE(T, BUF)                                                    \
    {                                                                    \
        const uint4* gs = bpanel + (T) * 512 + wave * 128 + lane;        \
        gload_lds16(gs,      &b_lds[BUF][wave * 128]);                   \
        gload_lds16(gs + 64, &b_lds[BUF][wave * 128 + 64]);              \
    }

    // one tile's compute+store (W values passed in regs)
#define TCOMP(T, WC0, WC1)                                               \
    {                                                                    \
        uint4 bb[8];                                                     \
        _Pragma("unroll")                                                \
        for (int s = 0; s < 8; ++s)                                      \
            bb[s] = b_lds[(T) & 3][s * 64 + lane];                       \
        f32x4 acc00 = {0.f,0.f,0.f,0.f}, acc01 = {0.f,0.f,0.f,0.f};      \
        f32x4 acc10 = {0.f,0.f,0.f,0.f}, acc11 = {0.f,0.f,0.f,0.f};      \
        _Pragma("unroll")                                                \
        for (int s = 0; s < 4; ++s) {                                    \
            bf16x8 b0 = __builtin_bit_cast(bf16x8, bb[s]);               \
            bf16x8 b1 = __builtin_bit_cast(bf16x8, bb[s + 4]);           \
            acc00 = __builtin_amdgcn_mfma_f32_16x16x32_bf16(aA[s],     b0, acc00, 0, 0, 0); \
            acc01 = __builtin_amdgcn_mfma_f32_16x16x32_bf16(aA[s + 4], b1, acc01, 0, 0, 0); \
            acc10 = __builtin_amdgcn_mfma_f32_16x16x32_bf16(aB[s],     b0, acc10, 0, 0, 0); \
            acc11 = __builtin_amdgcn_mfma_f32_16x16x32_bf16(aB[s + 4], b1, acc11, 0, 0, 0); \
        }                                                                \
        _Pragma("unroll")                                                \
        for (int r = 0; r < 4; ++r) {                                    \
            float v0 = msk0[r] ? 0.0f : (acc00[r] + acc01[r] + WC0[r]);  \
            float v1 = msk1[r] ? 0.0f : (acc10[r] + acc11[r] + WC1[r]);  \
            out[ooff0[r] + (T) * 16] = v0;                               \
            out[ooff1[r] + (T) * 16] = v1;                               \
        }                                                                \
    }

    // phase: compute tiles T,T+1; stage T+2,T+3; prefetch W T+4,T+5
#define PHASE(T, PF, LAST)                                               \
    {                                                                    \
        float wcA0[4], wcA1[4], wcB0[4], wcB1[4];                        \
        _Pragma("unroll")                                                \
        for (int r = 0; r < 4; ++r) {                                    \
            wcA0[r] = wv0[(T) & 3][r];     wcA1[r] = wv1[(T) & 3][r];    \
            wcB0[r] = wv0[(T + 1) & 3][r]; wcB1[r] = wv1[(T + 1) & 3][r];\
        }                                                                \
        if (PF) {                                                        \
            _Pragma("unroll")                                            \
            for (int r = 0; r < 4; ++r) {                                \
                float v0 = 0.0f, v1 = 0.0f;                              \
                if (!msk0[r]) v0 = W[woff0[r] + ((T) + 4) * 16];         \
                if (!msk1[r]) v1 = W[woff1[r] + ((T) + 4) * 16];         \
                wv0[(T) & 3][r] = v0;                                    \
                wv1[(T) & 3][r] = v1;                                    \
                float u0 = 0.0f, u1 = 0.0f;                              \
                if (!msk0[r]) u0 = W[woff0[r] + ((T) + 5) * 16];         \
                if (!msk1[r]) u1 = W[woff1[r] + ((T) + 5) * 16];         \
                wv0[(T + 1) & 3][r] = u0;                                \
                wv1[(T + 1) & 3][r] = u1;                                \
            }                                                            \
        }                                                                \
        if (!(LAST)) {                                                   \
            STAGE((T) + 2, ((T) + 2) & 3);                               \
            STAGE((T) + 3, ((T) + 3) & 3);                               \
        }                                                                \
        __builtin_amdgcn_sched_barrier(0);                               \
        TCOMP((T),     wcA0, wcA1);                                      \
        TCOMP((T) + 1, wcB0, wcB1);                                      \
        if (!(LAST)) {                                                   \
            /* 16 stores are the newest VMEM ops; everything older       \
               (W-pref + 4 stage loads) must be retired. */              \
            asm volatile("s_waitcnt vmcnt(16)" ::: "memory");            \
            __builtin_amdgcn_s_barrier();                                \
        }                                                                \
    }

    STAGE(0, 0);
    STAGE(1, 1);
    __syncthreads();   // one-time full drain: tiles 0,1 staged

    PHASE(0,  1, 0);
    PHASE(2,  1, 0);
    PHASE(4,  1, 0);
    PHASE(6,  1, 0);
    PHASE(8,  1, 0);
    PHASE(10, 1, 0);
    PHASE(12, 0, 0);   // no W prefetch (would read past col range)
    PHASE(14, 0, 1);   // last: no stage, no barrier
#undef PHASE
#undef TCOMP
#undef STAGE
}

extern "C" void kernel_launch(void* const* d_in, const int* in_sizes, int n_in,
                              void* d_out, int out_size, void* d_ws, size_t ws_size,
                              hipStream_t stream) {
    (void)in_sizes; (void)n_in; (void)out_size; (void)ws_size;

    const int*   x    = (const int*)d_in[0];
    const int*   mask = (const int*)d_in[1];
    const float* W    = (const float*)d_in[2];
    const float* A    = (const float*)d_in[3];
    const float* B    = (const float*)d_in[4];
    float*       out  = (float*)d_out;

    unsigned short* Bfrag = (unsigned short*)d_ws;   // 2 MiB

    prep_B_kernel<<<dim3(512), dim3(256), 0, stream>>>(B, Bfrag);

    dim3 grid(NTOK / TPB, NCOL / CPB);   // (64, 16) = 1024 blocks
    emb_lora_mfma<<<grid, dim3(256), 0, stream>>>(x, mask, W, A, Bfrag, out);
}

// Round 23
// 48.818 us; speedup vs baseline: 1.2869x; 1.1363x over previous
//
#include <hip/hip_runtime.h>
#include <stdint.h>

#define NTOK 8192
#define NCOL 4096     // DIM == VOCAB
#define RANK 256
#define TPB  128      // tokens per block (4 waves x 32 tokens)
#define CPB  256      // cols per block (16 col-tiles)

typedef __attribute__((ext_vector_type(8))) short bf16x8;
typedef __attribute__((ext_vector_type(4))) float f32x4;

__device__ __forceinline__ unsigned short f2bf(float f) {
    unsigned int u = __float_as_uint(f);
    u += 0x7fffu + ((u >> 16) & 1u);   // RNE
    return (unsigned short)(u >> 16);
}

// async global->LDS, 16B per lane; LDS dest = uniform base + lane*16 (m104)
__device__ __forceinline__ void gload_lds16(const uint4* g, uint4* l) {
    __builtin_amdgcn_global_load_lds(
        (const __attribute__((address_space(1))) void*)g,
        (__attribute__((address_space(3))) void*)l, 16, 0, 0);
}

// ---- combined pre-pass ----
// blocks [0, 1024): A fp32 [4096][256] -> bf16 row-major (Abf, 2 MiB, L2-resident)
// blocks [1024, 1536): B fp32 [256][4096] -> bf16 MFMA-B-fragment order
//   frag layout: flat uint4 index = (ct*8 + ks)*64 + lane, 8 bf16 each:
//     element j = B[ks*32 + (lane>>4)*8 + j][ct*16 + (lane&15)]
__global__ __launch_bounds__(256) void prep_kernel(
    const float* __restrict__ A, const float* __restrict__ B,
    unsigned short* __restrict__ Abf, unsigned short* __restrict__ Bfrag)
{
    if (blockIdx.x < 1024) {
        int i = blockIdx.x * 256 + threadIdx.x;
        float4 v = reinterpret_cast<const float4*>(A)[i];
        ushort4 o;
        o.x = f2bf(v.x); o.y = f2bf(v.y); o.z = f2bf(v.z); o.w = f2bf(v.w);
        reinterpret_cast<ushort4*>(Abf)[i] = o;
    } else {
        int gt = (blockIdx.x - 1024) * 256 + threadIdx.x;
        int ct = gt >> 9;
        int rem = gt & 511;
        int ks = rem >> 6;
        int ln = rem & 63;
        int col = ct * 16 + (ln & 15);
        int kb  = ks * 32 + ((ln >> 4) << 3);
        unsigned short pk[8];
        #pragma unroll
        for (int j = 0; j < 8; ++j)
            pk[j] = f2bf(B[(size_t)(kb + j) * NCOL + col]);
        uint4 o;
        o.x = (unsigned)pk[0] | ((unsigned)pk[1] << 16);
        o.y = (unsigned)pk[2] | ((unsigned)pk[3] << 16);
        o.z = (unsigned)pk[4] | ((unsigned)pk[5] << 16);
        o.w = (unsigned)pk[6] | ((unsigned)pk[7] << 16);
        reinterpret_cast<uint4*>(Bfrag)[gt] = o;
    }
}

// ---- main: fused gather + LoRA GEMM + W add + mask ----
// r17 structure exactly (best: 49.09 us — LDS-staged B via global_load_lds,
// 2-tile phases with 4 staging buffers, W-ring depth 4 exec-masked,
// counted vmcnt(16) + raw barrier) + T5 probe: s_setprio(1) around the
// MFMA clusters (zero-risk; expected null per the T5 regime gate).
__global__ __launch_bounds__(256) void emb_lora_mfma(
    const int* __restrict__ x,
    const int* __restrict__ mask,
    const float* __restrict__ W,
    const unsigned short* __restrict__ Abf,
    const unsigned short* __restrict__ Bfrag,
    float* __restrict__ out)
{
    __shared__ int s_idx[TPB];
    __shared__ int s_msk[TPB];
    __shared__ uint4 b_lds[4][512];   // 4 x 8 KB staging buffers

    const int tid  = threadIdx.x;
    const int lane = tid & 63;
    const int wave = tid >> 6;        // wave owns tokens [wave*32, wave*32+32)
    const int tok0 = blockIdx.x * TPB;
    const int col0 = blockIdx.y * CPB;

    if (tid < TPB) {
        s_idx[tid] = x[tok0 + tid];
        s_msk[tid] = mask[tok0 + tid];
    }
    __syncthreads();

    // A fragments for both token groups (A-operand row = lane&15)
    const int a0row = s_idx[wave * 32 + (lane & 15)];
    const int a1row = s_idx[wave * 32 + 16 + (lane & 15)];
    const unsigned short* ap0 = Abf + (size_t)a0row * RANK + ((lane >> 4) << 3);
    const unsigned short* ap1 = Abf + (size_t)a1row * RANK + ((lane >> 4) << 3);
    bf16x8 aA[8], aB[8];
    #pragma unroll
    for (int s = 0; s < 8; ++s) {
        aA[s] = *reinterpret_cast<const bf16x8*>(ap0 + s * 32);
        aB[s] = *reinterpret_cast<const bf16x8*>(ap1 + s * 32);
    }

    // per-thread epilogue state: group g covers rows wave*32+g*16+(lane>>4)*4+r
    const int colb = col0 + (lane & 15);
    int msk0[4], msk1[4];
    unsigned woff0[4], woff1[4], ooff0[4], ooff1[4];
    #pragma unroll
    for (int r = 0; r < 4; ++r) {
        int row0 = wave * 32 + ((lane >> 4) << 2) + r;
        int row1 = row0 + 16;
        msk0[r] = s_msk[row0];
        msk1[r] = s_msk[row1];
        woff0[r] = (unsigned)s_idx[row0] * NCOL + colb;
        woff1[r] = (unsigned)s_idx[row1] * NCOL + colb;
        ooff0[r] = (unsigned)(tok0 + row0) * NCOL + colb;
        ooff1[r] = (unsigned)(tok0 + row1) * NCOL + colb;
    }

    // block's 16 col-tiles start at global col-tile blockIdx.y*16
    const uint4* bpanel = reinterpret_cast<const uint4*>(Bfrag)
                          + (size_t)(blockIdx.y * 16) * 512;

    // W prefetch rings, depth 4, exec-masked loads
    // (explicit `if`, NOT ternary — r3: speculation doubled FETCH_SIZE)
    float wv0[4][4], wv1[4][4];
    #pragma unroll
    for (int p = 0; p < 4; ++p) {
        #pragma unroll
        for (int r = 0; r < 4; ++r) {
            float v0 = 0.0f, v1 = 0.0f;
            if (!msk0[r]) v0 = W[woff0[r] + p * 16];
            if (!msk1[r]) v1 = W[woff1[r] + p * 16];
            wv0[p][r] = v0;
            wv1[p][r] = v1;
        }
    }

    // stage: wave stages its 2 KB of tile T into buffer BUF (async)
#define STAGE(T, BUF)                                                    \
    {                                                                    \
        const uint4* gs = bpanel + (T) * 512 + wave * 128 + lane;        \
        gload_lds16(gs,      &b_lds[BUF][wave * 128]);                   \
        gload_lds16(gs + 64, &b_lds[BUF][wave * 128 + 64]);              \
    }

    // one tile's compute+store (W values passed in regs)
#define TCOMP(T, WC0, WC1)                                               \
    {                                                                    \
        uint4 bb[8];                                                     \
        _Pragma("unroll")                                                \
        for (int s = 0; s < 8; ++s)                                      \
            bb[s] = b_lds[(T) & 3][s * 64 + lane];                       \
        f32x4 acc00 = {0.f,0.f,0.f,0.f}, acc01 = {0.f,0.f,0.f,0.f};      \
        f32x4 acc10 = {0.f,0.f,0.f,0.f}, acc11 = {0.f,0.f,0.f,0.f};      \
        __builtin_amdgcn_s_setprio(1);                                   \
        _Pragma("unroll")                                                \
        for (int s = 0; s < 4; ++s) {                                    \
            bf16x8 b0 = __builtin_bit_cast(bf16x8, bb[s]);               \
            bf16x8 b1 = __builtin_bit_cast(bf16x8, bb[s + 4]);           \
            acc00 = __builtin_amdgcn_mfma_f32_16x16x32_bf16(aA[s],     b0, acc00, 0, 0, 0); \
            acc01 = __builtin_amdgcn_mfma_f32_16x16x32_bf16(aA[s + 4], b1, acc01, 0, 0, 0); \
            acc10 = __builtin_amdgcn_mfma_f32_16x16x32_bf16(aB[s],     b0, acc10, 0, 0, 0); \
            acc11 = __builtin_amdgcn_mfma_f32_16x16x32_bf16(aB[s + 4], b1, acc11, 0, 0, 0); \
        }                                                                \
        __builtin_amdgcn_s_setprio(0);                                   \
        _Pragma("unroll")                                                \
        for (int r = 0; r < 4; ++r) {                                    \
            float v0 = msk0[r] ? 0.0f : (acc00[r] + acc01[r] + WC0[r]);  \
            float v1 = msk1[r] ? 0.0f : (acc10[r] + acc11[r] + WC1[r]);  \
            out[ooff0[r] + (T) * 16] = v0;                               \
            out[ooff1[r] + (T) * 16] = v1;                               \
        }                                                                \
    }

    // phase: compute tiles T,T+1; stage T+2,T+3; prefetch W T+4,T+5
#define PHASE(T, PF, LAST)                                               \
    {                                                                    \
        float wcA0[4], wcA1[4], wcB0[4], wcB1[4];                        \
        _Pragma("unroll")                                                \
        for (int r = 0; r < 4; ++r) {                                    \
            wcA0[r] = wv0[(T) & 3][r];     wcA1[r] = wv1[(T) & 3][r];    \
            wcB0[r] = wv0[(T + 1) & 3][r]; wcB1[r] = wv1[(T + 1) & 3][r];\
        }                                                                \
        if (PF) {                                                        \
            _Pragma("unroll")                                            \
            for (int r = 0; r < 4; ++r) {                                \
                float v0 = 0.0f, v1 = 0.0f;                              \
                if (!msk0[r]) v0 = W[woff0[r] + ((T) + 4) * 16];         \
                if (!msk1[r]) v1 = W[woff1[r] + ((T) + 4) * 16];         \
                wv0[(T) & 3][r] = v0;                                    \
                wv1[(T) & 3][r] = v1;                                    \
                float u0 = 0.0f, u1 = 0.0f;                              \
                if (!msk0[r]) u0 = W[woff0[r] + ((T) + 5) * 16];         \
                if (!msk1[r]) u1 = W[woff1[r] + ((T) + 5) * 16];         \
                wv0[(T + 1) & 3][r] = u0;                                \
                wv1[(T + 1) & 3][r] = u1;                                \
            }                                                            \
        }                                                                \
        if (!(LAST)) {                                                   \
            STAGE((T) + 2, ((T) + 2) & 3);                               \
            STAGE((T) + 3, ((T) + 3) & 3);                               \
        }                                                                \
        __builtin_amdgcn_sched_barrier(0);                               \
        TCOMP((T),     wcA0, wcA1);                                      \
        TCOMP((T) + 1, wcB0, wcB1);                                      \
        if (!(LAST)) {                                                   \
            /* 16 stores are the newest VMEM ops; everything older       \
               (W-pref + 4 stage loads) must be retired. */              \
            asm volatile("s_waitcnt vmcnt(16)" ::: "memory");            \
            __builtin_amdgcn_s_barrier();                                \
        }                                                                \
    }

    STAGE(0, 0);
    STAGE(1, 1);
    __syncthreads();   // one-time full drain: tiles 0,1 staged

    PHASE(0,  1, 0);
    PHASE(2,  1, 0);
    PHASE(4,  1, 0);
    PHASE(6,  1, 0);
    PHASE(8,  1, 0);
    PHASE(10, 1, 0);
    PHASE(12, 0, 0);   // no W prefetch (would read past col range)
    PHASE(14, 0, 1);   // last: no stage, no barrier
#undef PHASE
#undef TCOMP
#undef STAGE
}

extern "C" void kernel_launch(void* const* d_in, const int* in_sizes, int n_in,
                              void* d_out, int out_size, void* d_ws, size_t ws_size,
                              hipStream_t stream) {
    (void)in_sizes; (void)n_in; (void)out_size; (void)ws_size;

    const int*   x    = (const int*)d_in[0];
    const int*   mask = (const int*)d_in[1];
    const float* W    = (const float*)d_in[2];
    const float* A    = (const float*)d_in[3];
    const float* B    = (const float*)d_in[4];
    float*       out  = (float*)d_out;

    unsigned short* Abf   = (unsigned short*)d_ws;                       // 2 MiB
    unsigned short* Bfrag = (unsigned short*)((char*)d_ws + (2u << 20)); // 2 MiB

    prep_kernel<<<dim3(1536), dim3(256), 0, stream>>>(A, B, Abf, Bfrag);

    dim3 grid(NTOK / TPB, NCOL / CPB);   // (64, 16) = 1024 blocks
    emb_lora_mfma<<<grid, dim3(256), 0, stream>>>(x, mask, W, Abf, Bfrag, out);
}